// Round 2
// baseline (12278.667 us; speedup 1.0000x reference)
//
#include <hip/hip_runtime.h>
#include <hip/hip_cooperative_groups.h>
#include <cmath>
#include <cstdint>

namespace cg = cooperative_groups;

#define NT 256
#define GB 1024            // 4 blocks/CU on 256 CUs -> co-resident with launch_bounds
#define MAX_ROUNDS 64
#define SCAN_T 32
#define SCAN_IPB (NT*SCAN_T)   // 8192 items per scan block

// ---------------- fused cooperative MIS + cluster propagation ----------------
// a,b: min_rank double buffer; mA,mB: dilation masks; mis: MIS membership
// rcnt[r]: uncovered count after round r (pre-zeroed); present/scal pre-zeroed.
__global__ void __launch_bounds__(NT, 4)
k_mis_coop(int* a, int* b, int* mA, int* mB, int* mis,
           const int* __restrict__ row, const int* __restrict__ col,
           int n, int E, int* rcnt, int* present, int* scal)
{
  cg::grid_group g = cg::this_grid();
  const int tid = blockIdx.x*NT + threadIdx.x;
  const int nth = GB*NT;
  __shared__ int sh[NT];

  // init: rank = arange(n), mis = 0
  for(int v=tid; v<n; v+=nth){ a[v]=v; b[v]=v; mis[v]=0; }
  g.sync();

  for(int r=0; r<MAX_ROUNDS; ++r){
    // hop1: b = min(a, min_{row->col} a[row])   (b == a at entry)
    for(int e=tid; e<E; e+=nth){
      int s=a[row[e]]; int* d=&b[col[e]];
      if(s < *d) atomicMin(d, s);
    }
    g.sync();
    for(int v=tid; v<n; v+=nth) a[v]=b[v];
    g.sync();
    // hop2: a = min(b, min b[row])
    for(int e=tid; e<E; e+=nth){
      int s=b[row[e]]; int* d=&a[col[e]];
      if(s < *d) atomicMin(d, s);
    }
    g.sync();
    // mis |= (min_rank == rank);  seed dilation masks
    for(int v=tid; v<n; v+=nth){
      int m = mis[v] | (a[v]==v);
      mis[v]=m; mA[v]=m; mB[v]=m;
    }
    g.sync();
    // dilate hop1: mB |= mA[row]
    for(int e=tid; e<E; e+=nth){
      if(mA[row[e]] && !mB[col[e]]) mB[col[e]]=1;
    }
    g.sync();
    for(int v=tid; v<n; v+=nth) mA[v]=mB[v];
    g.sync();
    // dilate hop2: mA |= mB[row]
    for(int e=tid; e<E; e+=nth){
      if(mB[row[e]] && !mA[col[e]]) mA[col[e]]=1;
    }
    g.sync();
    // finalize: min_rank = covered ? n : rank ; count uncovered
    int unc=0;
    for(int v=tid; v<n; v+=nth){
      int cov=mA[v];
      int val = cov ? n : v;
      a[v]=val; b[v]=val;
      unc += !cov;
    }
    sh[threadIdx.x]=unc; __syncthreads();
    for(int off=NT/2; off>0; off>>=1){
      if(threadIdx.x<off) sh[threadIdx.x]+=sh[threadIdx.x+off];
      __syncthreads();
    }
    if(threadIdx.x==0 && sh[0]) atomicAdd(&rcnt[r], sh[0]);
    g.sync();
    if(rcnt[r]==0) break;   // exact convergence: all covered
  }

  // cluster propagation: min_rank = mis ? rank : n, propagate min 2 hops
  for(int v=tid; v<n; v+=nth){ int m = mis[v]? v : n; a[v]=m; b[v]=m; }
  g.sync();
  for(int e=tid; e<E; e+=nth){
    int s=a[row[e]]; int* d=&b[col[e]];
    if(s < *d) atomicMin(d, s);
  }
  g.sync();
  for(int v=tid; v<n; v+=nth) a[v]=b[v];
  g.sync();
  for(int e=tid; e<E; e+=nth){
    int s=b[row[e]]; int* d=&a[col[e]];
    if(s < *d) atomicMin(d, s);
  }
  g.sync();
  // mark present ranks + count c = sum(mis)
  int cm=0;
  for(int v=tid; v<n; v+=nth){
    int rv=a[v];
    if(rv<n) present[rv]=1;
    cm += mis[v];
  }
  sh[threadIdx.x]=cm; __syncthreads();
  for(int off=NT/2; off>0; off>>=1){
    if(threadIdx.x<off) sh[threadIdx.x]+=sh[threadIdx.x+off];
    __syncthreads();
  }
  if(threadIdx.x==0 && sh[0]) atomicAdd(&scal[0], sh[0]);
}

// ---------------- generic 3-pass exclusive scan over int array ----------------

__global__ void k_scan1(const int* A, int M, int* bsum){
  int t = threadIdx.x;
  long base = (long)blockIdx.x*SCAN_IPB + (long)t*SCAN_T;
  int s = 0;
  #pragma unroll
  for(int j=0;j<SCAN_T;j++){ long i=base+j; if(i<M) s += A[i]; }
  __shared__ int sh[NT];
  sh[t]=s; __syncthreads();
  for(int off=NT/2; off>0; off>>=1){ if(t<off) sh[t]+=sh[t+off]; __syncthreads(); }
  if(t==0) bsum[blockIdx.x]=sh[0];
}

__global__ void k_scan2(const int* bsum, int* bscan, int B, int* totalOut){
  __shared__ int sh[NT];
  int t = threadIdx.x;
  int carry = 0;
  for(int base=0; base<B; base+=NT){
    int i = base+t;
    int v = (i<B) ? bsum[i] : 0;
    sh[t]=v; __syncthreads();
    for(int off=1; off<NT; off<<=1){
      int x=0; if(t>=off) x=sh[t-off];
      __syncthreads();
      sh[t]+=x; __syncthreads();
    }
    int incl = sh[t];
    if(i<B) bscan[i] = carry + incl - v;   // exclusive
    carry += sh[NT-1];
    __syncthreads();
  }
  if(t==0 && totalOut) *totalOut = carry;
}

__global__ void k_scan3(const int* A, int M, const int* bscan, int* pref){
  int t = threadIdx.x;
  long base = (long)blockIdx.x*SCAN_IPB + (long)t*SCAN_T;
  int s = 0;
  #pragma unroll
  for(int j=0;j<SCAN_T;j++){ long i=base+j; if(i<M) s += A[i]; }
  __shared__ int sh[NT];
  sh[t]=s; __syncthreads();
  for(int off=1; off<NT; off<<=1){
    int x=0; if(t>=off) x=sh[t-off];
    __syncthreads();
    sh[t]+=x; __syncthreads();
  }
  int run = bscan[blockIdx.x] + (sh[t]-s);
  for(int j=0;j<SCAN_T;j++){
    long i=base+j;
    if(i<M){ pref[i]=run; run += A[i]; }
  }
}

// ---------------- clustering & pooling ----------------

__global__ void k_assign(const int* mr, const int* pref, int* cl, int* ccount, int n){
  int v = blockIdx.x*NT + threadIdx.x;
  if(v<n){
    int r = mr[v];
    int cid = (r<n) ? pref[r] : 0;
    cl[v]=cid;
    atomicAdd(&ccount[cid],1);
  }
}

__global__ void k_scatter_nodes(const int* cl, const int* cstart, int* cursor, int* nodeList, int n){
  int v = blockIdx.x*NT + threadIdx.x;
  if(v<n){
    int cid = cl[v];
    int pos = cstart[cid] + atomicAdd(&cursor[cid],1);
    nodeList[pos]=v;
  }
}

// one block per cluster; thread t = feature dim t (D==256==blockDim)
__global__ void k_pool_x(const float* __restrict__ x, const int* nodeList, const int* cstart,
                         const int* ccount, const int* scal, float* out, long out_size){
  int c = scal[0], U = scal[1];
  int t = threadIdx.x;
  for(int cid=blockIdx.x; cid<c; cid+=gridDim.x){
    float s = 0.f;
    if(cid<U){
      int st = cstart[cid], cn = ccount[cid];
      for(int i=0;i<cn;i++){
        int nd = nodeList[st+i];
        s += x[(size_t)nd*256 + t];
      }
    }
    long idx = (long)cid*256 + t;
    if(idx < out_size) out[idx]=s;
  }
}

__global__ void k_edge_pool(const int* row, const int* col, const float* attr, const int* cl,
                            const int* scal, float* dense, unsigned int* bits, int E, long CMsq){
  int c = scal[0];
  int stride = gridDim.x*NT;
  for(int e = blockIdx.x*NT + threadIdx.x; e<E; e+=stride){
    long key = (long)cl[row[e]]*c + cl[col[e]];
    if(key < CMsq){
      atomicAdd(&dense[key], attr[e]);
      atomicOr(&bits[key>>5], 1u<<((int)key&31));
    }
  }
}

__device__ __forceinline__ int cell_pred(long k, int c, const unsigned int* bits){
  if(!((bits[k>>5]>>((int)k&31))&1u)) return 0;
  int r = (int)(k/c), q = (int)(k - (long)r*c);
  return r!=q;   // remove self-loops
}

__global__ void k_cscan1(const unsigned int* bits, const int* scal, int* bsum, long CMsq){
  int c = scal[0];
  long M = (long)c*c; if(M>CMsq) M=CMsq;
  int t = threadIdx.x;
  long base = (long)blockIdx.x*SCAN_IPB + (long)t*SCAN_T;
  int s = 0;
  for(int j=0;j<SCAN_T;j++){ long i=base+j; if(i<M) s += cell_pred(i,c,bits); }
  __shared__ int sh[NT];
  sh[t]=s; __syncthreads();
  for(int off=NT/2; off>0; off>>=1){ if(t<off) sh[t]+=sh[t+off]; __syncthreads(); }
  if(t==0) bsum[blockIdx.x]=sh[0];
}

__global__ void k_cemit(const unsigned int* bits, const float* dense, const int* scal,
                        const int* bscan, float* out, long out_size, long CMsq){
  int c = scal[0]; int P = scal[2];
  long M = (long)c*c; if(M>CMsq) M=CMsq;
  long xoff = (long)c*256;
  int t = threadIdx.x;
  long base = (long)blockIdx.x*SCAN_IPB + (long)t*SCAN_T;
  int s = 0;
  for(int j=0;j<SCAN_T;j++){ long i=base+j; if(i<M) s += cell_pred(i,c,bits); }
  __shared__ int sh[NT];
  sh[t]=s; __syncthreads();
  for(int off=1; off<NT; off<<=1){
    int x=0; if(t>=off) x=sh[t-off];
    __syncthreads();
    sh[t]+=x; __syncthreads();
  }
  int run = bscan[blockIdx.x] + (sh[t]-s);
  for(int j=0;j<SCAN_T;j++){
    long i=base+j;
    if(i<M && cell_pred(i,c,bits)){
      int r=(int)(i/c), q=(int)(i-(long)r*c);
      long o0 = xoff + run;
      long o1 = xoff + (long)P + run;
      long o2 = xoff + 2L*(long)P + run;
      if(o0<out_size) out[o0]=(float)r;
      if(o1<out_size) out[o1]=(float)q;
      if(o2<out_size) out[o2]=dense[i];
      run++;
    }
  }
}

// ---------------- host ----------------

extern "C" void kernel_launch(void* const* d_in, const int* in_sizes, int n_in,
                              void* d_out, int out_size, void* d_ws, size_t ws_size,
                              hipStream_t stream){
  (void)n_in;
  const float* x     = (const float*)d_in[0];
  const int*   eidx  = (const int*)d_in[1];
  const float* eattr = (const float*)d_in[2];
  const int D = 256;
  int n = in_sizes[0]/D;
  int E = in_sizes[1]/2;
  const int* row = eidx;
  const int* col = eidx + E;

  // ---- workspace layout (256B-aligned bump allocator) ----
  char* p = (char*)d_ws;
  auto alloc = [&](size_t bytes)->char*{ char* r=p; p += (bytes+255)&~(size_t)255; return r; };
  int* a     = (int*)alloc((size_t)n*4);
  int* b     = (int*)alloc((size_t)n*4);
  int* mA    = (int*)alloc((size_t)n*4);   // reused as nodeList
  int* mB    = (int*)alloc((size_t)n*4);   // reused as cl
  int* pref  = (int*)alloc((size_t)n*4);   // reused as clusterStart
  int* bsum  = (int*)alloc(4096*4);
  int* bscan = (int*)alloc(4096*4);
  char* zstart = p;                         // everything below is zeroed each call
  int* mis     = (int*)alloc((size_t)n*4);
  int* present = (int*)alloc((size_t)n*4);
  int* ccount  = (int*)alloc((size_t)n*4);
  int* cursor  = (int*)alloc((size_t)n*4);
  int* rcnt    = (int*)alloc(MAX_ROUNDS*4);
  int* scal    = (int*)alloc(64);           // [0]=c (mis count), [1]=U (#unique), [2]=P (#pooled edges)

  size_t used   = (size_t)(p-(char*)d_ws);
  size_t remain = (ws_size > used+4096) ? ws_size-used-4096 : 0;
  size_t cells  = remain/5;                 // dense f32 (4B) + bitmask (0.125B) + slack
  long CM = (long)std::sqrt((double)cells);
  while(CM>1 && CM*CM > (long)cells) CM--;
  if(CM>4096) CM=4096;
  if(CM<1) CM=1;
  long CMsq = CM*CM;
  unsigned int* bits = (unsigned int*)alloc(((size_t)CMsq/32 + 2)*4);
  float* dense       = (float*)alloc((size_t)CMsq*4);
  size_t zbytes = (size_t)(p - zstart);
  hipMemsetAsync(zstart, 0, zbytes, stream);

  int NB  = (n+NT-1)/NT;
  int EB  = 1024;
  int NBs = (n+SCAN_IPB-1)/SCAN_IPB;
  int CB  = (int)((CMsq+SCAN_IPB-1)/SCAN_IPB);

  // ---- fused cooperative k-MIS + cluster min-propagation ----
  {
    void* cargs[] = { (void*)&a, (void*)&b, (void*)&mA, (void*)&mB, (void*)&mis,
                      (void*)&row, (void*)&col, (void*)&n, (void*)&E,
                      (void*)&rcnt, (void*)&present, (void*)&scal };
    hipLaunchCooperativeKernel((const void*)k_mis_coop, dim3(GB), dim3(NT),
                               cargs, 0, stream);
  }

  // ---- unique(min_rank) -> dense cluster ids (sorted order) ----
  k_scan1<<<NBs,NT,0,stream>>>(present,n,bsum);
  k_scan2<<<1,NT,0,stream>>>(bsum,bscan,NBs,scal+1);      // U = #unique
  k_scan3<<<NBs,NT,0,stream>>>(present,n,bscan,pref);
  k_assign<<<NB,NT,0,stream>>>(a,pref,mB/*cl*/,ccount,n);

  // ---- counting sort nodes by cluster (for x_pooled) ----
  k_scan1<<<NBs,NT,0,stream>>>(ccount,n,bsum);
  k_scan2<<<1,NT,0,stream>>>(bsum,bscan,NBs,nullptr);
  k_scan3<<<NBs,NT,0,stream>>>(ccount,n,bscan,pref/*clusterStart*/);
  k_scatter_nodes<<<NB,NT,0,stream>>>(mB,pref,cursor,mA/*nodeList*/,n);

  // ---- x_pooled = segment_sum(x, cluster, c) ----
  k_pool_x<<<1024,NT,0,stream>>>(x,mA,pref,ccount,scal,(float*)d_out,(long)out_size);

  // ---- pooled adjacency: dense c x c accumulate, then sorted compaction ----
  k_edge_pool<<<EB,NT,0,stream>>>(row,col,eattr,mB,scal,dense,bits,E,CMsq);
  k_cscan1<<<CB,NT,0,stream>>>(bits,scal,bsum,CMsq);
  k_scan2 <<<1,NT,0,stream>>>(bsum,bscan,CB,scal+2);      // P = #kept pooled edges
  k_cemit <<<CB,NT,0,stream>>>(bits,dense,scal,bscan,(float*)d_out,(long)out_size,CMsq);
}

// Round 3
// 3491.783 us; speedup vs baseline: 3.5164x; 3.5164x over previous
//
#include <hip/hip_runtime.h>
#include <cmath>
#include <cstdint>

#define NT 256
#define EGRID 1024
#define MAX_ROUNDS 26
#define SCAN_T 32
#define SCAN_IPB (NT*SCAN_T)   // 8192 items per scan block

// ---------------- setup ----------------

__global__ void k_init(int* a, int* b, int n){
  int v = blockIdx.x*NT + threadIdx.x;
  if(v<n){ a[v]=v; b[v]=v; }
}

__global__ void k_copyE(const int* row, const int* col, int2* L, int E, int* lcnt0){
  int stride = gridDim.x*NT;
  for(int e = blockIdx.x*NT + threadIdx.x; e<E; e+=stride)
    L[e] = make_int2(row[e], col[e]);
  if(blockIdx.x==0 && threadIdx.x==0) *lcnt0 = E;
}

// ---------------- per-round kernels (compacted list) ----------------

// b[col] min= a[row]  (b==a on entry)
__global__ void k_hop(int* dst, const int* src, const int2* L, const int* pE,
                      const int* rcnt, int round){
  if(round>0 && rcnt[round-1]==0) return;
  int E = *pE;
  int stride = gridDim.x*NT;
  for(int e = blockIdx.x*NT + threadIdx.x; e<E; e+=stride){
    int2 ed = L[e];
    int s = src[ed.x];
    if(s < dst[ed.y]) atomicMin(&dst[ed.y], s);
  }
}

__global__ void k_copy_n(int* dst, const int* src, int n, const int* rcnt, int round){
  if(round>0 && rcnt[round-1]==0) return;
  int v = blockIdx.x*NT + threadIdx.x;
  if(v<n) dst[v]=src[v];
}

// dilation hop1 from new MIS (a[x]==x): seed + 1-hop into d2
__global__ void k_dil1(const int* a, int* d2, const int2* L, const int* pE,
                       const int* rcnt, int round){
  if(round>0 && rcnt[round-1]==0) return;
  int E = *pE;
  int stride = gridDim.x*NT;
  for(int e = blockIdx.x*NT + threadIdx.x; e<E; e+=stride){
    int2 ed = L[e];
    if(a[ed.x]==ed.x){ d2[ed.x]=1; d2[ed.y]=1; }
  }
}

// dilation hop2: cover[col] |= (d2[row] | new(row))
__global__ void k_dil2(const int* a, const int* d2, int* cover, const int2* L, const int* pE,
                       const int* rcnt, int round){
  if(round>0 && rcnt[round-1]==0) return;
  int E = *pE;
  int stride = gridDim.x*NT;
  for(int e = blockIdx.x*NT + threadIdx.x; e<E; e+=stride){
    int2 ed = L[e];
    if((d2[ed.x] || a[ed.x]==ed.x) && !cover[ed.y]) cover[ed.y]=1;
  }
}

// finalize (nodes) + compact (edges) fused. compact predicate uses cover|d2 which
// equals the final coverage regardless of node-loop progress (race-free).
__global__ void k_fincomp(int* a, int* b, int* mis, int* cover, int* d2, int n,
                          const int2* Lsrc, const int* pE, int2* Ldst, int* dstCnt,
                          int* rcnt, int round){
  if(round>0 && rcnt[round-1]==0) return;
  int nth = gridDim.x*NT;
  int tid = blockIdx.x*NT + threadIdx.x;
  // ---- node phase: fold coverage, reset ranks, count uncovered ----
  int unc = 0;
  for(int v=tid; v<n; v+=nth){
    int nw = (a[v]==v);
    if(nw) mis[v]=1;
    int cov = cover[v] | d2[v] | nw;
    cover[v]=cov; d2[v]=0;
    int val = cov ? n : v;
    a[v]=val; b[v]=val;
    unc += !cov;
  }
  __shared__ int sh[NT];
  sh[threadIdx.x]=unc; __syncthreads();
  for(int off=NT/2; off>0; off>>=1){
    if(threadIdx.x<off) sh[threadIdx.x]+=sh[threadIdx.x+off];
    __syncthreads();
  }
  if(threadIdx.x==0 && sh[0]) atomicAdd(&rcnt[round], sh[0]);
  // ---- compact phase (wave-aggregated append) ----
  int E = *pE;
  int lane = threadIdx.x & 63;
  long wid = (long)((blockIdx.x*NT + threadIdx.x)>>6);
  long nwv = (long)(nth>>6);
  for(long base = wid*64; base < E; base += nwv*64){
    int e = (int)(base + lane);
    int2 ed = e<E ? Lsrc[e] : make_int2(0,0);
    bool keep = false;
    if(e<E){
      int cx = cover[ed.x] | d2[ed.x];   // d2 already 0 or being zeroed; cover holds final
      int cy = cover[ed.y] | d2[ed.y];
      keep = (!cx) || (!cy);
    }
    unsigned long long m = __ballot(keep);
    int cnt = __popcll(m);
    int pos = 0;
    if(lane==0 && cnt) pos = atomicAdd(dstCnt, cnt);
    pos = __shfl(pos, 0);
    if(keep){
      int myoff = __popcll(m & ((1ull<<lane)-1ull));
      Ldst[pos+myoff] = ed;
    }
  }
}

// ---------------- cluster phase (full edge list, original arrays) ----------------

__global__ void k_cluster_init(const int* mis, int* a, int* b, int n){
  int v = blockIdx.x*NT + threadIdx.x;
  if(v<n){ int m = mis[v] ? v : n; a[v]=m; b[v]=m; }
}

__global__ void k_scat_min_rc(int* dst, const int* src, const int* row, const int* col, int E){
  int stride = gridDim.x*NT;
  for(int e = blockIdx.x*NT + threadIdx.x; e<E; e+=stride){
    int s = src[row[e]];
    if(s < dst[col[e]]) atomicMin(&dst[col[e]], s);
  }
}

__global__ void k_copy_plain(int* dst, const int* src, int n){
  int v = blockIdx.x*NT + threadIdx.x;
  if(v<n) dst[v]=src[v];
}

__global__ void k_mark(const int* mr, const int* mis, int* present, int* cmis, int n){
  int v = blockIdx.x*NT + threadIdx.x;
  int m = 0;
  if(v<n){
    int r = mr[v];
    if(r<n) present[r]=1;
    m = mis[v];
  }
  __shared__ int sh[NT];
  sh[threadIdx.x]=m; __syncthreads();
  for(int off=NT/2; off>0; off>>=1){
    if(threadIdx.x<off) sh[threadIdx.x]+=sh[threadIdx.x+off];
    __syncthreads();
  }
  if(threadIdx.x==0 && sh[0]) atomicAdd(cmis, sh[0]);
}

// ---------------- generic 3-pass exclusive scan ----------------

__global__ void k_scan1(const int* A, int M, int* bsum){
  int t = threadIdx.x;
  long base = (long)blockIdx.x*SCAN_IPB + (long)t*SCAN_T;
  int s = 0;
  #pragma unroll
  for(int j=0;j<SCAN_T;j++){ long i=base+j; if(i<M) s += A[i]; }
  __shared__ int sh[NT];
  sh[t]=s; __syncthreads();
  for(int off=NT/2; off>0; off>>=1){ if(t<off) sh[t]+=sh[t+off]; __syncthreads(); }
  if(t==0) bsum[blockIdx.x]=sh[0];
}

__global__ void k_scan2(const int* bsum, int* bscan, int B, int* totalOut){
  __shared__ int sh[NT];
  int t = threadIdx.x;
  int carry = 0;
  for(int base=0; base<B; base+=NT){
    int i = base+t;
    int v = (i<B) ? bsum[i] : 0;
    sh[t]=v; __syncthreads();
    for(int off=1; off<NT; off<<=1){
      int x=0; if(t>=off) x=sh[t-off];
      __syncthreads();
      sh[t]+=x; __syncthreads();
    }
    int incl = sh[t];
    if(i<B) bscan[i] = carry + incl - v;   // exclusive
    carry += sh[NT-1];
    __syncthreads();
  }
  if(t==0 && totalOut) *totalOut = carry;
}

__global__ void k_scan3(const int* A, int M, const int* bscan, int* pref){
  int t = threadIdx.x;
  long base = (long)blockIdx.x*SCAN_IPB + (long)t*SCAN_T;
  int s = 0;
  #pragma unroll
  for(int j=0;j<SCAN_T;j++){ long i=base+j; if(i<M) s += A[i]; }
  __shared__ int sh[NT];
  sh[t]=s; __syncthreads();
  for(int off=1; off<NT; off<<=1){
    int x=0; if(t>=off) x=sh[t-off];
    __syncthreads();
    sh[t]+=x; __syncthreads();
  }
  int run = bscan[blockIdx.x] + (sh[t]-s);
  for(int j=0;j<SCAN_T;j++){
    long i=base+j;
    if(i<M){ pref[i]=run; run += A[i]; }
  }
}

// ---------------- clustering & pooling ----------------

__global__ void k_assign(const int* mr, const int* pref, int* cl, int* ccount, int n){
  int v = blockIdx.x*NT + threadIdx.x;
  if(v<n){
    int r = mr[v];
    int cid = (r<n) ? pref[r] : 0;
    cl[v]=cid;
    atomicAdd(&ccount[cid],1);
  }
}

__global__ void k_scatter_nodes(const int* cl, const int* cstart, int* cursor, int* nodeList, int n){
  int v = blockIdx.x*NT + threadIdx.x;
  if(v<n){
    int cid = cl[v];
    int pos = cstart[cid] + atomicAdd(&cursor[cid],1);
    nodeList[pos]=v;
  }
}

__global__ void k_pool_x(const float* __restrict__ x, const int* nodeList, const int* cstart,
                         const int* ccount, const int* scal, float* out, long out_size){
  int c = scal[0], U = scal[1];
  int t = threadIdx.x;
  for(int cid=blockIdx.x; cid<c; cid+=gridDim.x){
    float s = 0.f;
    if(cid<U){
      int st = cstart[cid], cn = ccount[cid];
      for(int i=0;i<cn;i++){
        int nd = nodeList[st+i];
        s += x[(size_t)nd*256 + t];
      }
    }
    long idx = (long)cid*256 + t;
    if(idx < out_size) out[idx]=s;
  }
}

__global__ void k_edge_pool(const int* row, const int* col, const float* attr, const int* cl,
                            const int* scal, float* dense, unsigned int* bits, int E, long CMsq){
  int c = scal[0];
  int stride = gridDim.x*NT;
  for(int e = blockIdx.x*NT + threadIdx.x; e<E; e+=stride){
    long key = (long)cl[row[e]]*c + cl[col[e]];
    if(key < CMsq){
      atomicAdd(&dense[key], attr[e]);
      atomicOr(&bits[key>>5], 1u<<((int)key&31));
    }
  }
}

__device__ __forceinline__ int cell_pred(long k, int c, const unsigned int* bits){
  if(!((bits[k>>5]>>((int)k&31))&1u)) return 0;
  int r = (int)(k/c), q = (int)(k - (long)r*c);
  return r!=q;   // remove self-loops
}

__global__ void k_cscan1(const unsigned int* bits, const int* scal, int* bsum, long CMsq){
  int c = scal[0];
  long M = (long)c*c; if(M>CMsq) M=CMsq;
  int t = threadIdx.x;
  long base = (long)blockIdx.x*SCAN_IPB + (long)t*SCAN_T;
  int s = 0;
  for(int j=0;j<SCAN_T;j++){ long i=base+j; if(i<M) s += cell_pred(i,c,bits); }
  __shared__ int sh[NT];
  sh[t]=s; __syncthreads();
  for(int off=NT/2; off>0; off>>=1){ if(t<off) sh[t]+=sh[t+off]; __syncthreads(); }
  if(t==0) bsum[blockIdx.x]=sh[0];
}

__global__ void k_cemit(const unsigned int* bits, const float* dense, const int* scal,
                        const int* bscan, float* out, long out_size, long CMsq){
  int c = scal[0]; int P = scal[2];
  long M = (long)c*c; if(M>CMsq) M=CMsq;
  long xoff = (long)c*256;
  int t = threadIdx.x;
  long base = (long)blockIdx.x*SCAN_IPB + (long)t*SCAN_T;
  int s = 0;
  for(int j=0;j<SCAN_T;j++){ long i=base+j; if(i<M) s += cell_pred(i,c,bits); }
  __shared__ int sh[NT];
  sh[t]=s; __syncthreads();
  for(int off=1; off<NT; off<<=1){
    int x=0; if(t>=off) x=sh[t-off];
    __syncthreads();
    sh[t]+=x; __syncthreads();
  }
  int run = bscan[blockIdx.x] + (sh[t]-s);
  for(int j=0;j<SCAN_T;j++){
    long i=base+j;
    if(i<M && cell_pred(i,c,bits)){
      int r=(int)(i/c), q=(int)(i-(long)r*c);
      long o0 = xoff + run;
      long o1 = xoff + (long)P + run;
      long o2 = xoff + 2L*(long)P + run;
      if(o0<out_size) out[o0]=(float)r;
      if(o1<out_size) out[o1]=(float)q;
      if(o2<out_size) out[o2]=dense[i];
      run++;
    }
  }
}

// ---------------- host ----------------

extern "C" void kernel_launch(void* const* d_in, const int* in_sizes, int n_in,
                              void* d_out, int out_size, void* d_ws, size_t ws_size,
                              hipStream_t stream){
  (void)n_in;
  const float* x     = (const float*)d_in[0];
  const int*   eidx  = (const int*)d_in[1];
  const float* eattr = (const float*)d_in[2];
  const int D = 256;
  int n = in_sizes[0]/D;
  int E = in_sizes[1]/2;
  const int* row = eidx;
  const int* col = eidx + E;

  // ---- workspace layout ----
  char* p = (char*)d_ws;
  auto alloc = [&](size_t bytes)->char*{ char* r=p; p += (bytes+255)&~(size_t)255; return r; };
  int2* LA   = (int2*)alloc((size_t)E*8);
  int2* LB   = (int2*)alloc((size_t)E*8);
  int* a     = (int*)alloc((size_t)n*4);
  int* b     = (int*)alloc((size_t)n*4);
  int* cl    = (int*)alloc((size_t)n*4);
  int* nodeList = (int*)alloc((size_t)n*4);
  int* pref  = (int*)alloc((size_t)n*4);
  int* bsum  = (int*)alloc(4096*4);
  int* bscan = (int*)alloc(4096*4);
  char* zstart = p;                         // zeroed each call
  int* mis     = (int*)alloc((size_t)n*4);
  int* cover   = (int*)alloc((size_t)n*4);
  int* d2      = (int*)alloc((size_t)n*4);
  int* present = (int*)alloc((size_t)n*4);
  int* ccount  = (int*)alloc((size_t)n*4);
  int* cursor  = (int*)alloc((size_t)n*4);
  int* rcnt    = (int*)alloc((MAX_ROUNDS+2)*4);
  int* lcnt    = (int*)alloc((MAX_ROUNDS+2)*4);
  int* scal    = (int*)alloc(64);           // [0]=c, [1]=U, [2]=P

  size_t used   = (size_t)(p-(char*)d_ws);
  size_t remain = (ws_size > used+4096) ? ws_size-used-4096 : 0;
  size_t cells  = remain/5;
  long CM = (long)std::sqrt((double)cells);
  while(CM>1 && CM*CM > (long)cells) CM--;
  if(CM>4096) CM=4096;
  if(CM<1) CM=1;
  long CMsq = CM*CM;
  unsigned int* bits = (unsigned int*)alloc(((size_t)CMsq/32 + 2)*4);
  float* dense       = (float*)alloc((size_t)CMsq*4);
  size_t zbytes = (size_t)(p - zstart);
  hipMemsetAsync(zstart, 0, zbytes, stream);

  int NB  = (n+NT-1)/NT;
  int NBs = (n+SCAN_IPB-1)/SCAN_IPB;
  int CB  = (int)((CMsq+SCAN_IPB-1)/SCAN_IPB);

  // ---- init ----
  k_init <<<NB,NT,0,stream>>>(a,b,n);
  k_copyE<<<EGRID,NT,0,stream>>>(row,col,LA,E,&lcnt[0]);

  // ---- Luby k-MIS (k=2) with cumulative edge-list compaction ----
  for(int r=0;r<MAX_ROUNDS;r++){
    int2* Ls = (r&1) ? LB : LA;
    int2* Ld = (r&1) ? LA : LB;
    k_hop    <<<EGRID,NT,0,stream>>>(b,a,Ls,&lcnt[r],rcnt,r);       // hop1
    k_copy_n <<<NB,NT,0,stream>>>(a,b,n,rcnt,r);
    k_hop    <<<EGRID,NT,0,stream>>>(a,b,Ls,&lcnt[r],rcnt,r);       // hop2
    k_dil1   <<<EGRID,NT,0,stream>>>(a,d2,Ls,&lcnt[r],rcnt,r);
    k_dil2   <<<EGRID,NT,0,stream>>>(a,d2,cover,Ls,&lcnt[r],rcnt,r);
    k_fincomp<<<EGRID,NT,0,stream>>>(a,b,mis,cover,d2,n,Ls,&lcnt[r],Ld,&lcnt[r+1],rcnt,r);
  }

  // ---- cluster propagation: min_rank = mis? rank : n, 2 hops over full graph ----
  k_cluster_init<<<NB,NT,0,stream>>>(mis,a,b,n);
  k_scat_min_rc <<<EGRID,NT,0,stream>>>(b,a,row,col,E);
  k_copy_plain  <<<NB,NT,0,stream>>>(a,b,n);
  k_scat_min_rc <<<EGRID,NT,0,stream>>>(a,b,row,col,E);

  // ---- unique(min_rank) -> dense cluster ids ----
  k_mark <<<NB,NT,0,stream>>>(a,mis,present,scal,n);
  k_scan1<<<NBs,NT,0,stream>>>(present,n,bsum);
  k_scan2<<<1,NT,0,stream>>>(bsum,bscan,NBs,scal+1);
  k_scan3<<<NBs,NT,0,stream>>>(present,n,bscan,pref);
  k_assign<<<NB,NT,0,stream>>>(a,pref,cl,ccount,n);

  // ---- counting sort nodes by cluster ----
  k_scan1<<<NBs,NT,0,stream>>>(ccount,n,bsum);
  k_scan2<<<1,NT,0,stream>>>(bsum,bscan,NBs,nullptr);
  k_scan3<<<NBs,NT,0,stream>>>(ccount,n,bscan,pref);
  k_scatter_nodes<<<NB,NT,0,stream>>>(cl,pref,cursor,nodeList,n);

  // ---- x_pooled ----
  k_pool_x<<<1024,NT,0,stream>>>(x,nodeList,pref,ccount,scal,(float*)d_out,(long)out_size);

  // ---- pooled adjacency ----
  k_edge_pool<<<EGRID,NT,0,stream>>>(row,col,eattr,cl,scal,dense,bits,E,CMsq);
  k_cscan1<<<CB,NT,0,stream>>>(bits,scal,bsum,CMsq);
  k_scan2 <<<1,NT,0,stream>>>(bsum,bscan,CB,scal+2);
  k_cemit <<<CB,NT,0,stream>>>(bits,dense,scal,bscan,(float*)d_out,(long)out_size,CMsq);
}